// Round 1
// baseline (366.516 us; speedup 1.0000x reference)
//
#include <hip/hip_runtime.h>

// ---------------------------------------------------------------------------
// SAGE 3-layer GNN, fp32.
//   Per layer: S = X@W_self + b ; P = X@W_neigh  (one dual GEMM kernel)
//              h[i] = act( S[i] + (sum_{j in N_in(i)} P[j]) / max(deg_i,1) )
//   CSR (deg, row_start, edge_src sorted by dst) built once, reused 3 layers.
//   Readout fused into layer-3 aggregation (global atomics into 16x64 sums).
// ---------------------------------------------------------------------------

#define DH 64
#define NG 16

__global__ void deg_count_kernel(const int* __restrict__ dst, int* __restrict__ deg, int E) {
    int i = blockIdx.x * blockDim.x + threadIdx.x;
    if (i < E) atomicAdd(&deg[dst[i]], 1);
}

// single-block exclusive prefix scan over deg -> row_start (and cursor copy)
__global__ void scan_kernel(const int* __restrict__ deg, int* __restrict__ row_start,
                            int* __restrict__ cursor, int M) {
    __shared__ int sdata[1024];
    __shared__ int s_base;
    int tid = threadIdx.x;
    if (tid == 0) s_base = 0;
    __syncthreads();
    for (int base = 0; base < M; base += 1024) {
        int v = (base + tid < M) ? deg[base + tid] : 0;
        sdata[tid] = v;
        __syncthreads();
        for (int off = 1; off < 1024; off <<= 1) {
            int t = (tid >= off) ? sdata[tid - off] : 0;
            __syncthreads();
            sdata[tid] += t;
            __syncthreads();
        }
        int excl = sdata[tid] - v;
        if (base + tid < M) {
            int rs = s_base + excl;
            row_start[base + tid] = rs;
            cursor[base + tid] = rs;
        }
        __syncthreads();
        if (tid == 1023) s_base += sdata[1023];
        __syncthreads();
    }
    if (tid == 0) row_start[M] = s_base;
}

__global__ void scatter_kernel(const int* __restrict__ src, const int* __restrict__ dst,
                               int* __restrict__ cursor, int* __restrict__ edge_src, int E) {
    int i = blockIdx.x * blockDim.x + threadIdx.x;
    if (i < E) {
        int d = dst[i];
        int p = atomicAdd(&cursor[d], 1);
        edge_src[p] = src[i];
    }
}

// S = X@Wself + b ; P = X@Wneigh.  X: M x K row-major, W: K x 64 row-major.
// block = 256 threads, tile = 64 rows x 64 cols, each thread 4 rows x 4 cols x 2 mats.
template <int K>
__global__ __launch_bounds__(256) void gemm_dual_kernel(
    const float* __restrict__ X, const float* __restrict__ Ws_g,
    const float* __restrict__ Wn_g, const float* __restrict__ bias,
    float* __restrict__ S, float* __restrict__ P, int M) {
    __shared__ float Xs[64][68];   // stride 68: 16B-aligned float4 rows, banks ok
    __shared__ float Ws[64][68];
    __shared__ float Wn[64][68];
    int tid = threadIdx.x;
    int row0 = blockIdx.x * 64;
    int cx = tid & 15;    // col group: cols cx + 16*i
    int ry = tid >> 4;    // row group: rows 4*ry + j
    float acc_s[4][4] = {{0.f}};
    float acc_n[4][4] = {{0.f}};

    for (int kc = 0; kc < K; kc += 64) {
#pragma unroll
        for (int it = 0; it < 4; ++it) {
            int q = tid + 256 * it;       // 0..1023
            int row = q >> 4;             // 0..63
            int k4 = (q & 15) * 4;        // 0..60
            float4 xv;
            int gr = row0 + row;
            if (gr < M)
                xv = *reinterpret_cast<const float4*>(&X[(size_t)gr * K + kc + k4]);
            else
                xv = make_float4(0.f, 0.f, 0.f, 0.f);
            *reinterpret_cast<float4*>(&Xs[row][k4]) = xv;
            float4 wv = *reinterpret_cast<const float4*>(&Ws_g[(size_t)(kc + row) * 64 + k4]);
            *reinterpret_cast<float4*>(&Ws[row][k4]) = wv;
            float4 nv = *reinterpret_cast<const float4*>(&Wn_g[(size_t)(kc + row) * 64 + k4]);
            *reinterpret_cast<float4*>(&Wn[row][k4]) = nv;
        }
        __syncthreads();
#pragma unroll 4
        for (int kk = 0; kk < 64; ++kk) {
            float a[4], bs[4], bn[4];
#pragma unroll
            for (int j = 0; j < 4; ++j) a[j] = Xs[ry * 4 + j][kk];
#pragma unroll
            for (int i = 0; i < 4; ++i) {
                bs[i] = Ws[kk][cx + 16 * i];
                bn[i] = Wn[kk][cx + 16 * i];
            }
#pragma unroll
            for (int j = 0; j < 4; ++j)
#pragma unroll
                for (int i = 0; i < 4; ++i) {
                    acc_s[j][i] += a[j] * bs[i];
                    acc_n[j][i] += a[j] * bn[i];
                }
        }
        __syncthreads();
    }

#pragma unroll
    for (int j = 0; j < 4; ++j) {
        int r = row0 + ry * 4 + j;
        if (r < M) {
#pragma unroll
            for (int i = 0; i < 4; ++i) {
                int c = cx + 16 * i;
                S[(size_t)r * DH + c] = acc_s[j][i] + bias[c];
                P[(size_t)r * DH + c] = acc_n[j][i];
            }
        }
    }
}

// one wave (64 lanes) per node; lane = dim. Gathers P rows via CSR.
template <bool RELU, bool READOUT>
__global__ __launch_bounds__(256) void agg_kernel(
    const float* __restrict__ S, const float* __restrict__ P,
    const int* __restrict__ row_start, const int* __restrict__ edge_src,
    const int* __restrict__ deg, float* __restrict__ H,
    const int* __restrict__ graph_id, float* __restrict__ gsum,
    float* __restrict__ gcnt, int M) {
    int lane = threadIdx.x & 63;
    int n = blockIdx.x * 4 + (threadIdx.x >> 6);
    if (n >= M) return;
    int e0 = row_start[n], e1 = row_start[n + 1];
    float sum = 0.f;
    int e = e0;
    for (; e + 4 <= e1; e += 4) {   // 4 edges in flight for MLP
        int s0 = edge_src[e + 0];
        int s1 = edge_src[e + 1];
        int s2 = edge_src[e + 2];
        int s3 = edge_src[e + 3];
        float p0 = P[(size_t)s0 * DH + lane];
        float p1 = P[(size_t)s1 * DH + lane];
        float p2 = P[(size_t)s2 * DH + lane];
        float p3 = P[(size_t)s3 * DH + lane];
        sum += p0; sum += p1; sum += p2; sum += p3;
    }
    for (; e < e1; ++e) sum += P[(size_t)edge_src[e] * DH + lane];
    float inv = 1.0f / fmaxf((float)deg[n], 1.0f);
    float val = S[(size_t)n * DH + lane] + sum * inv;
    if (RELU) val = fmaxf(val, 0.f);
    H[(size_t)n * DH + lane] = val;
    if (READOUT) {
        int g = graph_id[n];
        atomicAdd(&gsum[g * DH + lane], val);
        if (lane == 0) atomicAdd(&gcnt[g], 1.0f);
    }
}

// single block of 1024: out_feat = gsum/cnt ; out = out_feat @ W_cls + b_cls
__global__ __launch_bounds__(1024) void readout_kernel(
    const float* __restrict__ gsum, const float* __restrict__ gcnt,
    const float* __restrict__ Wc, const float* __restrict__ bc,
    float* __restrict__ out, float* __restrict__ out_feat) {
    __shared__ float ofs[NG][DH];
    int tid = threadIdx.x;
    int g = tid >> 6, d = tid & 63;
    float of = gsum[tid] / fmaxf(gcnt[g], 1.0f);
    out_feat[tid] = of;
    ofs[g][d] = of;
    __syncthreads();
    if (tid < NG * 2) {
        int gg = tid >> 1, cc = tid & 1;
        float acc = bc[cc];
#pragma unroll 8
        for (int dd = 0; dd < DH; ++dd) acc += ofs[gg][dd] * Wc[dd * 2 + cc];
        out[gg * 2 + cc] = acc;
    }
}

extern "C" void kernel_launch(void* const* d_in, const int* in_sizes, int n_in,
                              void* d_out, int out_size, void* d_ws, size_t ws_size,
                              hipStream_t stream) {
    const float* feat     = (const float*)d_in[0];
    const int*   src      = (const int*)d_in[1];
    const int*   dst      = (const int*)d_in[2];
    const int*   graph_id = (const int*)d_in[3];
    const float* Ws1 = (const float*)d_in[4];
    const float* Wn1 = (const float*)d_in[5];
    const float* b1  = (const float*)d_in[6];
    const float* Ws2 = (const float*)d_in[7];
    const float* Wn2 = (const float*)d_in[8];
    const float* b2  = (const float*)d_in[9];
    const float* Ws3 = (const float*)d_in[10];
    const float* Wn3 = (const float*)d_in[11];
    const float* b3  = (const float*)d_in[12];
    const float* Wc  = (const float*)d_in[13];
    const float* bc  = (const float*)d_in[14];

    const int M = in_sizes[3];   // 10000 nodes
    const int E = in_sizes[1];   // 320000 edges

    float* out      = (float*)d_out;             // 16 x 2
    float* out_feat = out + NG * 2;              // 16 x 64
    float* Hbuf     = out_feat + NG * DH;        // 10000 x 64 (final h; also reused per layer)

    // workspace layout
    char* w = (char*)d_ws;
    size_t off = 0;
    auto carve = [&](size_t bytes) {
        size_t o = off;
        off = (off + bytes + 15) & ~(size_t)15;
        return o;
    };
    int*   deg      = (int*)  (w + carve((size_t)M * 4));
    float* gsum     = (float*)(w + carve((size_t)NG * DH * 4));
    float* gcnt     = (float*)(w + carve((size_t)NG * 4));
    size_t zero_bytes = off;                       // deg + gsum + gcnt
    int*   row_start = (int*)  (w + carve((size_t)(M + 1) * 4));
    int*   cursor    = (int*)  (w + carve((size_t)M * 4));
    int*   edge_src  = (int*)  (w + carve((size_t)E * 4));
    float* Sbuf      = (float*)(w + carve((size_t)M * DH * 4));
    float* Pbuf      = (float*)(w + carve((size_t)M * DH * 4));
    (void)ws_size; (void)n_in; (void)out_size;

    hipMemsetAsync(d_ws, 0, zero_bytes, stream);

    int eb = (E + 255) / 256;
    deg_count_kernel<<<eb, 256, 0, stream>>>(dst, deg, E);
    scan_kernel<<<1, 1024, 0, stream>>>(deg, row_start, cursor, M);
    scatter_kernel<<<eb, 256, 0, stream>>>(src, dst, cursor, edge_src, E);

    int gb = (M + 63) / 64;   // gemm blocks
    int ab = (M + 3) / 4;     // agg blocks

    // layer 1 (K=256), relu
    gemm_dual_kernel<256><<<gb, 256, 0, stream>>>(feat, Ws1, Wn1, b1, Sbuf, Pbuf, M);
    agg_kernel<true, false><<<ab, 256, 0, stream>>>(Sbuf, Pbuf, row_start, edge_src, deg,
                                                    Hbuf, graph_id, gsum, gcnt, M);
    // layer 2 (K=64), relu
    gemm_dual_kernel<64><<<gb, 256, 0, stream>>>(Hbuf, Ws2, Wn2, b2, Sbuf, Pbuf, M);
    agg_kernel<true, false><<<ab, 256, 0, stream>>>(Sbuf, Pbuf, row_start, edge_src, deg,
                                                    Hbuf, graph_id, gsum, gcnt, M);
    // layer 3 (K=64), no relu, fused readout accumulation
    gemm_dual_kernel<64><<<gb, 256, 0, stream>>>(Hbuf, Ws3, Wn3, b3, Sbuf, Pbuf, M);
    agg_kernel<false, true><<<ab, 256, 0, stream>>>(Sbuf, Pbuf, row_start, edge_src, deg,
                                                    Hbuf, graph_id, gsum, gcnt, M);

    readout_kernel<<<1, 1024, 0, stream>>>(gsum, gcnt, Wc, bc, out, out_feat);
}